// Round 4
// baseline (168.955 us; speedup 1.0000x reference)
//
#include <hip/hip_runtime.h>

#define NTYPES 6
#define HID 128
#define E_TILE 64

typedef short short8 __attribute__((ext_vector_type(8)));
typedef float f32x4 __attribute__((ext_vector_type(4)));

static __device__ __forceinline__ ushort f2bf(float f) {
    union { float f; unsigned u; } v; v.f = f;
    unsigned r = v.u + 0x7FFFu + ((v.u >> 16) & 1u);   // RNE
    return (ushort)(r >> 16);
}

// ws layout (ints):
//   [0..5] type counts, [8..14] type offsets, [16..21] cursors
//   [32 .. 32+E)       sorted edge ids (type-sorted)
//   [32+E .. 32+2E)    arr[e]  (arrival rank within tgt node)
//   [32+2E .. +N)      ncnt[N]
//   [.. +N+1)          noff[N+1]
//   [.. +256)          bsum[256]
// then 256B-aligned: Wt bf16 [6][128][256]
// then 256B-aligned: msgs bf16 [E][128]

__global__ void k_init(int* __restrict__ ws) {
    int i = threadIdx.x;
    if (i < NTYPES) { ws[i] = 0; ws[16 + i] = 0; }
}

__global__ void k_hist(const int* __restrict__ etype, int E, int* __restrict__ ws) {
    __shared__ int h[NTYPES];
    if (threadIdx.x < NTYPES) h[threadIdx.x] = 0;
    __syncthreads();
    int i = blockIdx.x * blockDim.x + threadIdx.x;
    if (i < E) atomicAdd(&h[etype[i] - 1], 1);
    __syncthreads();
    if (threadIdx.x < NTYPES) {
        int c = h[threadIdx.x];
        if (c) atomicAdd(&ws[threadIdx.x], c);
    }
}

__global__ void k_prefix(int* __restrict__ ws) {
    if (threadIdx.x == 0 && blockIdx.x == 0) {
        int acc = 0;
        for (int t = 0; t < NTYPES; ++t) { ws[8 + t] = acc; acc += ws[t]; }
        ws[8 + NTYPES] = acc;
    }
}

__global__ void k_fill(const int* __restrict__ etype, int E, int* __restrict__ ws) {
    __shared__ int lcnt[NTYPES];
    __shared__ int lbase[NTYPES];
    if (threadIdx.x < NTYPES) lcnt[threadIdx.x] = 0;
    __syncthreads();
    int i = blockIdx.x * blockDim.x + threadIdx.x;
    int t = 0, lr = 0;
    bool valid = (i < E);
    if (valid) {
        t = etype[i] - 1;
        lr = atomicAdd(&lcnt[t], 1);
    }
    __syncthreads();
    if (threadIdx.x < NTYPES) {
        int c = lcnt[threadIdx.x];
        lbase[threadIdx.x] = c ? atomicAdd(&ws[16 + threadIdx.x], c) : 0;
    }
    __syncthreads();
    if (valid) ws[32 + ws[8 + t] + lbase[t] + lr] = i;
}

// per-edge arrival rank within its target node (240k atomics over 200k addrs)
__global__ void k_ncount(const int* __restrict__ tgt, int E,
                         int* __restrict__ ncnt, int* __restrict__ arr) {
    int i = blockIdx.x * blockDim.x + threadIdx.x;
    if (i < E) arr[i] = atomicAdd(&ncnt[tgt[i]], 1);
}

// exclusive scan over ncnt[N]: 1024 elems/block
__global__ void k_scan1(const int* __restrict__ ncnt, int* __restrict__ noff,
                        int* __restrict__ bsum, int N) {
    __shared__ int s[256];
    const int b = blockIdx.x, t = threadIdx.x;
    const int base = b * 1024 + t * 4;
    int v[4];
    #pragma unroll
    for (int i = 0; i < 4; ++i) v[i] = (base + i < N) ? ncnt[base + i] : 0;
    int tsum = v[0] + v[1] + v[2] + v[3];
    s[t] = tsum;
    __syncthreads();
    for (int off = 1; off < 256; off <<= 1) {
        int x = (t >= off) ? s[t - off] : 0;
        __syncthreads();
        s[t] += x;
        __syncthreads();
    }
    if (t == 255) bsum[b] = s[255];
    int run = s[t] - tsum;
    #pragma unroll
    for (int i = 0; i < 4; ++i)
        if (base + i < N) { noff[base + i] = run; run += v[i]; }
}

__global__ void k_scan2(int* __restrict__ bsum, int nb) {
    __shared__ int s[256];
    const int t = threadIdx.x;
    int v = (t < nb) ? bsum[t] : 0;
    s[t] = v;
    __syncthreads();
    for (int off = 1; off < 256; off <<= 1) {
        int x = (t >= off) ? s[t - off] : 0;
        __syncthreads();
        s[t] += x;
        __syncthreads();
    }
    if (t < nb) bsum[t] = s[t] - v;   // exclusive
}

__global__ void k_scan3(int* __restrict__ noff, const int* __restrict__ bsum,
                        int N, int E) {
    int i = blockIdx.x * blockDim.x + threadIdx.x;
    if (i < N) noff[i] += bsum[i >> 10];
    if (i == 0) noff[N] = E;
}

// W f32 [6][256][128] -> Wt bf16 [6][128][256] (transposed per type)
__global__ void k_wconv(const float* __restrict__ W, ushort* __restrict__ Wt) {
    int t = blockIdx.x * blockDim.x + threadIdx.x;
    int n  = t & 127;
    int k8 = (t >> 7) & 31;
    int ty = t >> 12;
    if (ty >= NTYPES) return;
    const float* wp = W + ((size_t)ty * 256 + (size_t)k8 * 8) * HID + n;
    ushort tmp[8];
    #pragma unroll
    for (int j = 0; j < 8; ++j) tmp[j] = f2bf(wp[(size_t)j * HID]);
    *(short8*)(Wt + ((size_t)ty * HID + n) * 256 + k8 * 8) = *(short8*)tmp;
}

// One block = 64 edges of one type x 128 cols, K=256 via bf16 MFMA.
// MSGS=1: write per-edge bf16 message rows to msgs[dstrow] (no atomics).
// MSGS=0: fallback atomic scatter into out (round-3 behavior).
template <int MSGS>
__launch_bounds__(256, 4)
__global__ void k_edge_gemm(const float* __restrict__ state,
                            const int* __restrict__ src,
                            const int* __restrict__ tgt,
                            const ushort* __restrict__ Wt,
                            const int* __restrict__ ws,
                            const int* __restrict__ noff,
                            const int* __restrict__ arr,
                            ushort* __restrict__ msgs,
                            float* __restrict__ out) {
    __shared__ __align__(16) ushort Xs[E_TILE][264];   // 33792 B
    __shared__ int sN[E_TILE];
    __shared__ int tN[E_TILE];
    __shared__ int dstR[E_TILE];

    const int* offs   = ws + 8;
    const int* sorted = ws + 32;

    int tile = blockIdx.x;
    int ty, base = 0, cnt = 0;
    for (ty = 0; ty < NTYPES; ++ty) {
        int b = offs[ty], oend = offs[ty + 1];
        int nt = (oend - b + E_TILE - 1) / E_TILE;
        if (tile < nt) {
            base = b + tile * E_TILE;
            cnt = oend - base;
            if (cnt > E_TILE) cnt = E_TILE;
            break;
        }
        tile -= nt;
    }
    if (ty == NTYPES) return;

    const int tid = threadIdx.x;
    if (tid < E_TILE) {
        int sn = 0, tn = 0, dr = 0;
        if (tid < cnt) {
            int e = sorted[base + tid];
            sn = src[e]; tn = tgt[e];
            if (MSGS) dr = noff[tn] + arr[e];
        }
        sN[tid] = sn; tN[tid] = tn; dstR[tid] = dr;
    }
    __syncthreads();

    // ---- stage X = [state[src] | state[tgt]] as bf16 [64][256] ----
    {
        const int e = tid >> 2, q = tid & 3;
        if (e < cnt) {
            #pragma unroll
            for (int h = 0; h < 2; ++h) {
                const int node = h ? tN[e] : sN[e];
                const float* rp = state + (size_t)node * HID + q * 32;
                #pragma unroll
                for (int i = 0; i < 4; ++i) {
                    float4 v0 = *(const float4*)(rp + i * 8);
                    float4 v1 = *(const float4*)(rp + i * 8 + 4);
                    ushort tmp[8] = { f2bf(v0.x), f2bf(v0.y), f2bf(v0.z), f2bf(v0.w),
                                      f2bf(v1.x), f2bf(v1.y), f2bf(v1.z), f2bf(v1.w) };
                    *(short8*)&Xs[e][h * HID + q * 32 + i * 8] = *(short8*)tmp;
                }
            }
        } else {
            short8 z = (short8){0, 0, 0, 0, 0, 0, 0, 0};
            #pragma unroll
            for (int h = 0; h < 2; ++h)
                #pragma unroll
                for (int i = 0; i < 4; ++i)
                    *(short8*)&Xs[e][h * HID + q * 32 + i * 8] = z;
        }
    }
    __syncthreads();

    const int w  = tid >> 6;
    const int l  = tid & 63;
    const int lr = l & 15;
    const int lg = l >> 4;

    f32x4 acc[4][2];
    #pragma unroll
    for (int mf = 0; mf < 4; ++mf)
        #pragma unroll
        for (int nf = 0; nf < 2; ++nf)
            acc[mf][nf] = (f32x4){0.f, 0.f, 0.f, 0.f};

    const ushort* wb = Wt + ((size_t)ty * HID + w * 32 + lr) * 256 + 8 * lg;
    const ushort* xb = &Xs[lr][8 * lg];

    #pragma unroll
    for (int kk = 0; kk < 8; ++kk) {
        const int k0 = kk * 32;
        short8 b0 = *(const short8*)(wb + k0);
        short8 b1 = *(const short8*)(wb + 16 * 256 + k0);
        #pragma unroll
        for (int mf = 0; mf < 4; ++mf) {
            short8 a = *(const short8*)(xb + mf * 16 * 264 + k0);
            acc[mf][0] = __builtin_amdgcn_mfma_f32_16x16x32_bf16(a, b0, acc[mf][0], 0, 0, 0);
            acc[mf][1] = __builtin_amdgcn_mfma_f32_16x16x32_bf16(a, b1, acc[mf][1], 0, 0, 0);
        }
    }

    // ---- epilogue: acc -> Os (overlay on Xs, stride 132 floats) ----
    __syncthreads();
    float (*Os)[132] = (float (*)[132])&Xs[0][0];   // 64*132*4 = 33792 B exactly
    #pragma unroll
    for (int mf = 0; mf < 4; ++mf)
        #pragma unroll
        for (int nf = 0; nf < 2; ++nf)
            #pragma unroll
            for (int r = 0; r < 4; ++r)
                Os[mf * 16 + lg * 4 + r][w * 32 + nf * 16 + lr] = acc[mf][nf][r];
    __syncthreads();

    if (MSGS) {
        // write bf16 message rows, one plain store per 8 cols
        const int r8 = tid >> 4, cg = tid & 15;
        #pragma unroll
        for (int rr = 0; rr < 4; ++rr) {
            int row = rr * 16 + r8;
            if (row < cnt) {
                float4 a = *(const float4*)&Os[row][cg * 8];
                float4 b = *(const float4*)&Os[row][cg * 8 + 4];
                ushort tmp[8] = { f2bf(a.x), f2bf(a.y), f2bf(a.z), f2bf(a.w),
                                  f2bf(b.x), f2bf(b.y), f2bf(b.z), f2bf(b.w) };
                *(short8*)(msgs + (size_t)dstR[row] * HID + cg * 8) = *(short8*)tmp;
            }
        }
    } else {
        const int erow = tid >> 7;
        const int c    = tid & (HID - 1);
        for (int it = 0; it < E_TILE / 2; ++it) {
            int ee = it * 2 + erow;
            if (ee < cnt) atomicAdd(&out[(size_t)tN[ee] * HID + c], Os[ee][c]);
        }
    }
}

// each 64-lane group owns one node: sum msgs rows [noff[n],noff[n+1]), write once
__launch_bounds__(256)
__global__ void k_scatter(const ushort* __restrict__ msgs, const int* __restrict__ noff,
                          float* __restrict__ out, int N) {
    int node = blockIdx.x * 4 + (threadIdx.x >> 6);
    if (node >= N) return;
    int cp = threadIdx.x & 63;                 // column pair
    int s = noff[node], e = noff[node + 1];
    float a0 = 0.f, a1 = 0.f;
    for (int r = s; r < e; ++r) {
        unsigned u = *(const unsigned*)(msgs + (size_t)r * HID + cp * 2);
        union { unsigned u; float f; } lo, hi;
        lo.u = u << 16; hi.u = u & 0xFFFF0000u;
        a0 += lo.f; a1 += hi.f;
    }
    *(float2*)(out + (size_t)node * HID + cp * 2) = make_float2(a0, a1);
}

extern "C" void kernel_launch(void* const* d_in, const int* in_sizes, int n_in,
                              void* d_out, int out_size, void* d_ws, size_t ws_size,
                              hipStream_t stream) {
    const float* state = (const float*)d_in[0];
    const int*   edges = (const int*)d_in[1];
    const float* W     = (const float*)d_in[2];
    float* out = (float*)d_out;

    const int E = in_sizes[1] / 3;
    const int N = in_sizes[0] / HID;
    const int* etype = edges;
    const int* src   = edges + E;
    const int* tgt   = edges + 2 * E;
    int* ws = (int*)d_ws;

    // big-path layout
    int* sorted_arr = ws + 32;                 // [E] (implicit via k_fill)
    int* arr        = ws + 32 + E;             // [E]
    int* ncnt       = ws + 32 + 2 * E;         // [N]
    int* noff       = ws + 32 + 2 * E + N;     // [N+1]
    int* bsum       = noff + N + 1;            // [256]
    (void)sorted_arr;
    size_t intEnd   = (size_t)(32 + 2 * (size_t)E + 2 * (size_t)N + 1 + 256) * sizeof(int);
    size_t wtOff    = (intEnd + 255) & ~(size_t)255;
    size_t msgsOff  = ((wtOff + (size_t)NTYPES * HID * 256 * 2) + 255) & ~(size_t)255;
    size_t need     = msgsOff + (size_t)E * HID * 2;
    const int nb1   = (N + 1023) / 1024;
    const bool big  = (ws_size >= need) && (nb1 <= 256);

    const int nblocks = (E + E_TILE - 1) / E_TILE + NTYPES;

    if (big) {
        ushort* Wt   = (ushort*)((char*)d_ws + wtOff);
        ushort* msgs = (ushort*)((char*)d_ws + msgsOff);

        hipMemsetAsync(ncnt, 0, (size_t)N * sizeof(int), stream);
        k_init<<<1, 64, 0, stream>>>(ws);
        k_hist<<<(E + 255) / 256, 256, 0, stream>>>(etype, E, ws);
        k_prefix<<<1, 1, 0, stream>>>(ws);
        k_fill<<<(E + 255) / 256, 256, 0, stream>>>(etype, E, ws);
        k_ncount<<<(E + 255) / 256, 256, 0, stream>>>(tgt, E, ncnt, arr);
        k_scan1<<<nb1, 256, 0, stream>>>(ncnt, noff, bsum, N);
        k_scan2<<<1, 256, 0, stream>>>(bsum, nb1);
        k_scan3<<<(N + 255) / 256, 256, 0, stream>>>(noff, bsum, N, E);
        k_wconv<<<(NTYPES * HID * 32) / 256, 256, 0, stream>>>(W, Wt);
        k_edge_gemm<1><<<nblocks, 256, 0, stream>>>(state, src, tgt, Wt, ws,
                                                    noff, arr, msgs, out);
        k_scatter<<<(N + 3) / 4, 256, 0, stream>>>(msgs, noff, out, N);
    } else {
        // fallback: round-3 layout + atomic scatter
        size_t wt_off = (((size_t)(32 + E) * sizeof(int)) + 255) & ~(size_t)255;
        ushort* Wt = (ushort*)((char*)d_ws + wt_off);

        hipMemsetAsync(d_out, 0, (size_t)out_size * sizeof(float), stream);
        k_init<<<1, 64, 0, stream>>>(ws);
        k_hist<<<(E + 255) / 256, 256, 0, stream>>>(etype, E, ws);
        k_prefix<<<1, 1, 0, stream>>>(ws);
        k_fill<<<(E + 255) / 256, 256, 0, stream>>>(etype, E, ws);
        k_wconv<<<(NTYPES * HID * 32) / 256, 256, 0, stream>>>(W, Wt);
        k_edge_gemm<0><<<nblocks, 256, 0, stream>>>(state, src, tgt, Wt, ws,
                                                    nullptr, nullptr, nullptr, out);
    }
}